// Round 7
// baseline (155.229 us; speedup 1.0000x reference)
//
#include <hip/hip_runtime.h>
#include <stdint.h>

typedef __bf16 bf16x8 __attribute__((ext_vector_type(8)));
typedef float  f32x4  __attribute__((ext_vector_type(4)));

#define E_DIM 1024
#define H_DIM 64
#define T_SEQ 4096
#define B_BAT 4
#define M_TOT (B_BAT * T_SEQ)   // 16384
#define NSPLIT 8                 // flash key splits

__device__ __forceinline__ uint32_t f2bf1(float f) {
    uint32_t u = __float_as_uint(f);
    return (u + 0x7FFFu + ((u >> 16) & 1u)) >> 16;
}
__device__ __forceinline__ uint32_t pk2(float lo, float hi) {
    return f2bf1(lo) | (f2bf1(hi) << 16);
}
__device__ __forceinline__ bf16x8 ldfrag(const ushort* p) {
    return __builtin_bit_cast(bf16x8, *(const uint4*)(p));
}
__device__ __forceinline__ bf16x8 u2f(uint4 u) {
    return __builtin_bit_cast(bf16x8, u);
}
__device__ __forceinline__ float bf2f(uint32_t u) {
    return __uint_as_float(u << 16);
}
// barrier that waits LDS only — global prefetch stays in flight
__device__ __forceinline__ void barrier_lgkm() {
    __builtin_amdgcn_s_waitcnt(0xC07F);   // vmcnt(63) expcnt(7) lgkmcnt(0)
    __builtin_amdgcn_s_barrier();
}

// ---------------- kernel 0: W fp32 -> frag-major bf16 -----------------------
// Wfm[s 16][nt 12][kc 2][lane 64][8].
// Wq rows (n<64) pre-scaled by log2(e)/sqrt(E) so softmax exp is a bare 2^x.
__global__ __launch_bounds__(256) void wcvt(const float* __restrict__ Wq,
                                            const float* __restrict__ Wk,
                                            const float* __restrict__ Wv,
                                            ushort* __restrict__ Wfm) {
    int g = blockIdx.x * 256 + threadIdx.x;   // 24576 threads
    int n = g >> 7;          // 0..191
    int k8 = g & 127;
    const float* src = (n < 64) ? (Wq + (size_t)n * E_DIM)
                     : (n < 128) ? (Wk + (size_t)(n - 64) * E_DIM)
                     : (Wv + (size_t)(n - 128) * E_DIM);
    float sc = (n < 64) ? 0.04508422f : 1.0f;   // log2(e)/32
    float4 a = *(const float4*)(src + k8 * 8);
    float4 b = *(const float4*)(src + k8 * 8 + 4);
    uint4 o;
    o.x = pk2(a.x * sc, a.y * sc); o.y = pk2(a.z * sc, a.w * sc);
    o.z = pk2(b.x * sc, b.y * sc); o.w = pk2(b.z * sc, b.w * sc);
    int s = k8 >> 3, kc = (k8 >> 2) & 1, qd = k8 & 3;
    int nt = n >> 4, lm = n & 15;
    int lane = qd * 16 + lm;
    *(uint4*)(Wfm + (((size_t)(s * 12 + nt) * 2 + kc) * 64 + lane) * 8) = o;
}

// ---------------- kernel 1: QKV projection ----------------------------------
// 32-row blocks, BK=64, 16 steps. 2-deep x pipeline + 1-step REGISTER
// prefetch of W frags (L2 latency overlaps previous step's MFMA).
__global__ __launch_bounds__(256, 2) void qkv(const float* __restrict__ x,
                                              const ushort* __restrict__ Wfm,
                                              ushort* __restrict__ Qfm,
                                              ushort* __restrict__ Kfm,
                                              ushort* __restrict__ Vfm) {
    __shared__ union {
        ushort a[2][32 * 72];
        struct { ushort c[32 * 136]; ushort vt[64 * 40]; } epi;
    } sm;
    const int tid = threadIdx.x;
    const int w = tid >> 6, l = tid & 63;
    const int lm = l & 15, qd = l >> 4;
    const int m0 = blockIdx.x * 32;

    f32x4 acc[2][3];
#pragma unroll
    for (int r2 = 0; r2 < 2; ++r2)
#pragma unroll
        for (int t = 0; t < 3; ++t) acc[r2][t] = (f32x4){0.f, 0.f, 0.f, 0.f};

    const int srow = tid >> 3, kseg = tid & 7;
    const float* xsrc = x + (size_t)(m0 + srow) * E_DIM + kseg * 8;
    const ushort* wbase = Wfm + (size_t)(w * 3) * 2 * 64 * 8 + l * 8;

    {
        float4 a0 = *(const float4*)xsrc;
        float4 a1 = *(const float4*)(xsrc + 4);
        uint4 u = {pk2(a0.x, a0.y), pk2(a0.z, a0.w), pk2(a1.x, a1.y), pk2(a1.z, a1.w)};
        *(uint4*)(&sm.a[0][srow * 72 + kseg * 8]) = u;
    }
    float4 xn0 = *(const float4*)(xsrc + 64);
    float4 xn1 = *(const float4*)(xsrc + 68);
    // preload W frags for step 0
    uint4 wc[6];
#pragma unroll
    for (int c = 0; c < 6; ++c)
        wc[c] = *(const uint4*)(wbase + (size_t)c * 64 * 8);
    __syncthreads();

    for (int s = 0; s < 16; ++s) {
        const int cb = s & 1, nb = cb ^ 1;
        float4 x20 = xn0, x21 = xn1;
        if (s < 14) {
            x20 = *(const float4*)(xsrc + (s + 2) * 64);
            x21 = *(const float4*)(xsrc + (s + 2) * 64 + 4);
        }
        // prefetch W frags for step s+1 (consumed next iteration)
        uint4 wn[6];
        if (s < 15) {
            const ushort* wp = wbase + (size_t)(s + 1) * 12 * 2 * 64 * 8;
#pragma unroll
            for (int c = 0; c < 6; ++c)
                wn[c] = *(const uint4*)(wp + (size_t)c * 64 * 8);
        }
        // A frags from LDS
        bf16x8 af[2][2];
#pragma unroll
        for (int r2 = 0; r2 < 2; ++r2)
#pragma unroll
            for (int kc = 0; kc < 2; ++kc)
                af[r2][kc] = ldfrag(&sm.a[cb][(r2 * 16 + lm) * 72 + kc * 32 + qd * 8]);
#pragma unroll
        for (int t = 0; t < 3; ++t)
#pragma unroll
            for (int kc = 0; kc < 2; ++kc)
#pragma unroll
                for (int r2 = 0; r2 < 2; ++r2)
                    acc[r2][t] = __builtin_amdgcn_mfma_f32_16x16x32_bf16(af[r2][kc], u2f(wc[t * 2 + kc]), acc[r2][t], 0, 0, 0);
        if (s < 15) {
            uint4 u = {pk2(xn0.x, xn0.y), pk2(xn0.z, xn0.w), pk2(xn1.x, xn1.y), pk2(xn1.z, xn1.w)};
            *(uint4*)(&sm.a[nb][srow * 72 + kseg * 8]) = u;
#pragma unroll
            for (int c = 0; c < 6; ++c) wc[c] = wn[c];
        }
        xn0 = x20; xn1 = x21;
        if (s < 15) barrier_lgkm();
    }
    __syncthreads();

#pragma unroll
    for (int r2 = 0; r2 < 2; ++r2)
#pragma unroll
        for (int t = 0; t < 3; ++t) {
            int gc = w * 48 + t * 16 + lm;
            int m = r2 * 16 + qd * 4;
#pragma unroll
            for (int rr = 0; rr < 4; ++rr) {
                ushort v = (ushort)f2bf1(acc[r2][t][rr]);
                if (gc < 128) sm.epi.c[(m + rr) * 136 + gc] = v;
                else          sm.epi.vt[(gc - 128) * 40 + (m + rr)] = v;
            }
        }
    __syncthreads();

    const int g16b = m0 >> 4;
    const int kt64 = m0 >> 6;
    const int tb   = (m0 >> 4) & 3;
    const int kcv  = (m0 >> 5) & 1;
#pragma unroll
    for (int ii = 0; ii < 3; ++ii) {
        int i = w + ii * 4;
        uint4 val;
        ushort* dst;
        if (i < 4) {
            int qt_l = i >> 1, kc = i & 1;
            val = *(const uint4*)(&sm.epi.c[(qt_l * 16 + lm) * 136 + kc * 32 + qd * 8]);
            dst = Qfm + (((size_t)(g16b + qt_l) * 2 + kc) * 64 + l) * 8;
        } else if (i < 8) {
            int j2 = i - 4, t_l = j2 >> 1, kc = j2 & 1;
            val = *(const uint4*)(&sm.epi.c[(t_l * 16 + lm) * 136 + 64 + kc * 32 + qd * 8]);
            dst = Kfm + (((size_t)((kt64 * 4 + tb + t_l) * 2 + kc)) * 64 + l) * 8;
        } else {
            int t = i - 8;
            val = *(const uint4*)(&sm.epi.vt[(t * 16 + lm) * 40 + qd * 8]);
            dst = Vfm + (((size_t)((kt64 * 4 + t) * 2 + kcv)) * 64 + l) * 8;
        }
        *(uint4*)dst = val;
    }
}

// ---------------- kernel 2: causal flash attention --------------------------
// 8-way key split, pair-balanced, exp2 folded into Wq, bf16 O partials,
// 1-iteration register prefetch of K frags (L2 latency hides under exp+PV).
__global__ __launch_bounds__(256, 4) void flash(const ushort* __restrict__ Qfm,
                                                const ushort* __restrict__ Kfm,
                                                const ushort* __restrict__ Vfm,
                                                ushort* __restrict__ Opart,
                                                float* __restrict__ lpart) {
    __shared__ ushort plds[4][16 * 72];
    const int tid = threadIdx.x;
    const int wv = tid >> 6, l = tid & 63;
    const int lm = l & 15, qd = l >> 4;
    const int pr = blockIdx.x;   // pair 0..31
    const int bt = blockIdx.y;
    const int h  = blockIdx.z;   // key split 0..7
    ushort* myp = plds[wv];

#pragma unroll 1
    for (int half = 0; half < 2; ++half) {
        const int qt = half ? (63 - pr) : pr;
        const size_t rowg = (size_t)bt * T_SEQ + qt * 64 + wv * 16;
        const int g16 = bt * 256 + qt * 4 + wv;

        bf16x8 qf0, qf1;
        {
            const ushort* qp = Qfm + ((size_t)g16 * 2) * 512 + l * 8;
            qf0 = ldfrag(qp);
            qf1 = ldfrag(qp + 512);
        }
        f32x4 o[4];
#pragma unroll
        for (int t = 0; t < 4; ++t) o[t] = (f32x4){0.f, 0.f, 0.f, 0.f};
        float lacc = 0.f;

        // preload K frags for first iteration
        uint4 kreg[8];
        if (h <= qt) {
            const ushort* kb = Kfm + ((size_t)(bt * 64 + h) * 8) * 512 + l * 8;
#pragma unroll
            for (int t = 0; t < 8; ++t) kreg[t] = *(const uint4*)(kb + t * 512);
        }

#pragma unroll 1
        for (int kt = h; kt <= qt; kt += NSPLIT) {
            const ushort* vb = Vfm + ((size_t)(bt * 64 + kt) * 8) * 512;
            f32x4 sf[4];
#pragma unroll
            for (int t = 0; t < 4; ++t) sf[t] = (f32x4){0.f, 0.f, 0.f, 0.f};
#pragma unroll
            for (int t = 0; t < 4; ++t) {
                sf[t] = __builtin_amdgcn_mfma_f32_16x16x32_bf16(u2f(kreg[t * 2 + 0]), qf0, sf[t], 0, 0, 0);
                sf[t] = __builtin_amdgcn_mfma_f32_16x16x32_bf16(u2f(kreg[t * 2 + 1]), qf1, sf[t], 0, 0, 0);
            }
            // prefetch next iteration's K frags (overlaps exp + LDS hop + PV)
            if (kt + NSPLIT <= qt) {
                const ushort* kb2 = Kfm + ((size_t)(bt * 64 + kt + NSPLIT) * 8) * 512 + l * 8;
#pragma unroll
                for (int t = 0; t < 8; ++t) kreg[t] = *(const uint4*)(kb2 + t * 512);
            }
            uint4 vu[4][2];
#pragma unroll
            for (int t = 0; t < 4; ++t) {
                vu[t][0] = *(const uint4*)(vb + (t * 2 + 0) * 512 + l * 8);
                vu[t][1] = *(const uint4*)(vb + (t * 2 + 1) * 512 + l * 8);
            }
            ushort* wp = myp + lm * 72 + qd * 4;
            if (kt != qt) {            // fully unmasked tile
#pragma unroll
                for (int t = 0; t < 4; ++t) {
                    float p0 = exp2f(sf[t][0]), p1 = exp2f(sf[t][1]);
                    float p2 = exp2f(sf[t][2]), p3 = exp2f(sf[t][3]);
                    lacc += (p0 + p1) + (p2 + p3);
                    *(uint2*)(wp + t * 16) = uint2{pk2(p0, p1), pk2(p2, p3)};
                }
            } else {                   // diagonal: t<wv full, t==wv tri, t>wv zero
#pragma unroll
                for (int t = 0; t < 4; ++t) {
                    if (t < wv) {
                        float p0 = exp2f(sf[t][0]), p1 = exp2f(sf[t][1]);
                        float p2 = exp2f(sf[t][2]), p3 = exp2f(sf[t][3]);
                        lacc += (p0 + p1) + (p2 + p3);
                        *(uint2*)(wp + t * 16) = uint2{pk2(p0, p1), pk2(p2, p3)};
                    } else if (t == wv) {
                        float p[4];
#pragma unroll
                        for (int rr = 0; rr < 4; ++rr) {
                            float pe = exp2f(sf[t][rr]);
                            if (qd * 4 + rr > lm) pe = 0.f;
                            lacc += pe;
                            p[rr] = pe;
                        }
                        *(uint2*)(wp + t * 16) = uint2{pk2(p[0], p[1]), pk2(p[2], p[3])};
                    } else {
                        *(uint2*)(wp + t * 16) = uint2{0u, 0u};
                    }
                }
            }
            __builtin_amdgcn_wave_barrier();
            __builtin_amdgcn_s_waitcnt(0xC07F);  // lgkmcnt(0): P committed (wave-private)
            __builtin_amdgcn_wave_barrier();
            bf16x8 pf0 = ldfrag(myp + lm * 72 + qd * 8);
            bf16x8 pf1 = ldfrag(myp + lm * 72 + 32 + qd * 8);
#pragma unroll
            for (int t = 0; t < 4; ++t) {
                o[t] = __builtin_amdgcn_mfma_f32_16x16x32_bf16(pf0, u2f(vu[t][0]), o[t], 0, 0, 0);
                o[t] = __builtin_amdgcn_mfma_f32_16x16x32_bf16(pf1, u2f(vu[t][1]), o[t], 0, 0, 0);
            }
            __builtin_amdgcn_wave_barrier();
        }
        lacc += __shfl_xor(lacc, 16);
        lacc += __shfl_xor(lacc, 32);

        ushort* ob = Opart + ((size_t)h * M_TOT + rowg) * 64;
#pragma unroll
        for (int t = 0; t < 4; ++t)
#pragma unroll
            for (int rr = 0; rr < 4; ++rr)
                ob[(size_t)(qd * 4 + rr) * 64 + t * 16 + lm] = (ushort)f2bf1(o[t][rr]);
        if (qd == 0) lpart[(size_t)h * M_TOT + rowg + lm] = lacc;
    }
}

// ---------------- kernel 3: combine split-8 bf16 partials -------------------
__global__ __launch_bounds__(256) void combine(const ushort* __restrict__ Opart,
                                               const float* __restrict__ lpart,
                                               float* __restrict__ out) {
    int i4 = blockIdx.x * 256 + threadIdx.x;   // 262144 quads of 4
    size_t base = (size_t)i4 * 4;
    int row = i4 >> 4;
    float ls = 0.f;
#pragma unroll
    for (int j = 0; j < NSPLIT; ++j) ls += lpart[(size_t)j * M_TOT + row];
    float s0 = 0.f, s1 = 0.f, s2 = 0.f, s3 = 0.f;
    const size_t SP = (size_t)M_TOT * 64;
#pragma unroll
    for (int j = 0; j < NSPLIT; ++j) {
        uint2 u = *(const uint2*)(Opart + (size_t)j * SP + base);
        s0 += bf2f(u.x & 0xFFFFu); s1 += bf2f(u.x >> 16);
        s2 += bf2f(u.y & 0xFFFFu); s3 += bf2f(u.y >> 16);
    }
    float inv = 1.0f / ls;
    float4 o = {s0 * inv, s1 * inv, s2 * inv, s3 * inv};
    *(float4*)(out + base) = o;
}

extern "C" void kernel_launch(void* const* d_in, const int* in_sizes, int n_in,
                              void* d_out, int out_size, void* d_ws, size_t ws_size,
                              hipStream_t stream) {
    const float* x  = (const float*)d_in[0];
    const float* Wq = (const float*)d_in[1];
    const float* Wk = (const float*)d_in[2];
    const float* Wv = (const float*)d_in[3];
    float* out = (float*)d_out;

    char* ws = (char*)d_ws;
    ushort* Wfm = (ushort*)(ws);                 // 384 KB
    ushort* Qfm = (ushort*)(ws + 393216);        // 2 MB
    ushort* Kfm = (ushort*)(ws + 2490368);       // 2 MB
    ushort* Vfm = (ushort*)(ws + 4587520);       // 2 MB
    ushort* Op  = (ushort*)(ws + 6684672);       // 8 splits x 2 MB bf16 = 16 MB
    float*  lp  = (float*) (ws + 23461888);      // 512 KB

    wcvt<<<96, 256, 0, stream>>>(Wq, Wk, Wv, Wfm);
    qkv<<<512, 256, 0, stream>>>(x, Wfm, Qfm, Kfm, Vfm);
    flash<<<dim3(32, B_BAT, NSPLIT), 256, 0, stream>>>(Qfm, Kfm, Vfm, Op, lp);
    combine<<<1024, 256, 0, stream>>>(Op, lp, out);
}

// Round 8
// 136.969 us; speedup vs baseline: 1.1333x; 1.1333x over previous
//
#include <hip/hip_runtime.h>
#include <stdint.h>

typedef __bf16 bf16x8 __attribute__((ext_vector_type(8)));
typedef float  f32x4  __attribute__((ext_vector_type(4)));

#define E_DIM 1024
#define H_DIM 64
#define T_SEQ 4096
#define B_BAT 4
#define M_TOT (B_BAT * T_SEQ)   // 16384
#define NSPLIT 8                 // flash key splits

__device__ __forceinline__ uint32_t f2bf1(float f) {
    uint32_t u = __float_as_uint(f);
    return (u + 0x7FFFu + ((u >> 16) & 1u)) >> 16;
}
__device__ __forceinline__ uint32_t pk2(float lo, float hi) {
    return f2bf1(lo) | (f2bf1(hi) << 16);
}
__device__ __forceinline__ bf16x8 ldfrag(const ushort* p) {
    return __builtin_bit_cast(bf16x8, *(const uint4*)(p));
}
__device__ __forceinline__ bf16x8 u2f(uint4 u) {
    return __builtin_bit_cast(bf16x8, u);
}
__device__ __forceinline__ float bf2f(uint32_t u) {
    return __uint_as_float(u << 16);
}
// barrier that waits LDS only — global prefetch stays in flight
__device__ __forceinline__ void barrier_lgkm() {
    __builtin_amdgcn_s_waitcnt(0xC07F);   // vmcnt(63) expcnt(7) lgkmcnt(0)
    __builtin_amdgcn_s_barrier();
}

// ---------------- kernel 0: W fp32 -> frag-major bf16 -----------------------
// Wfm[s 16][nt 12][kc 2][lane 64][8].
// Wq rows (n<64) pre-scaled by log2(e)/sqrt(E) so softmax exp is a bare 2^x.
__global__ __launch_bounds__(256) void wcvt(const float* __restrict__ Wq,
                                            const float* __restrict__ Wk,
                                            const float* __restrict__ Wv,
                                            ushort* __restrict__ Wfm) {
    int g = blockIdx.x * 256 + threadIdx.x;   // 24576 threads
    int n = g >> 7;          // 0..191
    int k8 = g & 127;
    const float* src = (n < 64) ? (Wq + (size_t)n * E_DIM)
                     : (n < 128) ? (Wk + (size_t)(n - 64) * E_DIM)
                     : (Wv + (size_t)(n - 128) * E_DIM);
    float sc = (n < 64) ? 0.04508422f : 1.0f;   // log2(e)/32
    float4 a = *(const float4*)(src + k8 * 8);
    float4 b = *(const float4*)(src + k8 * 8 + 4);
    uint4 o;
    o.x = pk2(a.x * sc, a.y * sc); o.y = pk2(a.z * sc, a.w * sc);
    o.z = pk2(b.x * sc, b.y * sc); o.w = pk2(b.z * sc, b.w * sc);
    int s = k8 >> 3, kc = (k8 >> 2) & 1, qd = k8 & 3;
    int nt = n >> 4, lm = n & 15;
    int lane = qd * 16 + lm;
    *(uint4*)(Wfm + (((size_t)(s * 12 + nt) * 2 + kc) * 64 + lane) * 8) = o;
}

// ---------------- kernel 1: QKV projection (R6 form, reverted) --------------
__global__ __launch_bounds__(256, 3) void qkv(const float* __restrict__ x,
                                              const ushort* __restrict__ Wfm,
                                              ushort* __restrict__ Qfm,
                                              ushort* __restrict__ Kfm,
                                              ushort* __restrict__ Vfm) {
    __shared__ union {
        ushort a[2][32 * 72];
        struct { ushort c[32 * 136]; ushort vt[64 * 40]; } epi;
    } sm;
    const int tid = threadIdx.x;
    const int w = tid >> 6, l = tid & 63;
    const int lm = l & 15, qd = l >> 4;
    const int m0 = blockIdx.x * 32;

    f32x4 acc[2][3];
#pragma unroll
    for (int r2 = 0; r2 < 2; ++r2)
#pragma unroll
        for (int t = 0; t < 3; ++t) acc[r2][t] = (f32x4){0.f, 0.f, 0.f, 0.f};

    const int srow = tid >> 3, kseg = tid & 7;
    const float* xsrc = x + (size_t)(m0 + srow) * E_DIM + kseg * 8;

    {
        float4 a0 = *(const float4*)xsrc;
        float4 a1 = *(const float4*)(xsrc + 4);
        uint4 u = {pk2(a0.x, a0.y), pk2(a0.z, a0.w), pk2(a1.x, a1.y), pk2(a1.z, a1.w)};
        *(uint4*)(&sm.a[0][srow * 72 + kseg * 8]) = u;
    }
    float4 xn0 = *(const float4*)(xsrc + 64);
    float4 xn1 = *(const float4*)(xsrc + 68);
    __syncthreads();

    for (int s = 0; s < 16; ++s) {
        const int cb = s & 1, nb = cb ^ 1;
        float4 x20 = xn0, x21 = xn1;
        if (s < 14) {
            x20 = *(const float4*)(xsrc + (s + 2) * 64);
            x21 = *(const float4*)(xsrc + (s + 2) * 64 + 4);
        }
        bf16x8 wf[3][2];
#pragma unroll
        for (int t = 0; t < 3; ++t)
#pragma unroll
            for (int kc = 0; kc < 2; ++kc)
                wf[t][kc] = ldfrag(Wfm + (((size_t)(s * 12 + w * 3 + t) * 2 + kc) * 64 + l) * 8);
        bf16x8 af[2][2];
#pragma unroll
        for (int r2 = 0; r2 < 2; ++r2)
#pragma unroll
            for (int kc = 0; kc < 2; ++kc)
                af[r2][kc] = ldfrag(&sm.a[cb][(r2 * 16 + lm) * 72 + kc * 32 + qd * 8]);
#pragma unroll
        for (int t = 0; t < 3; ++t)
#pragma unroll
            for (int kc = 0; kc < 2; ++kc)
#pragma unroll
                for (int r2 = 0; r2 < 2; ++r2)
                    acc[r2][t] = __builtin_amdgcn_mfma_f32_16x16x32_bf16(af[r2][kc], wf[t][kc], acc[r2][t], 0, 0, 0);
        if (s < 15) {
            uint4 u = {pk2(xn0.x, xn0.y), pk2(xn0.z, xn0.w), pk2(xn1.x, xn1.y), pk2(xn1.z, xn1.w)};
            *(uint4*)(&sm.a[nb][srow * 72 + kseg * 8]) = u;
        }
        xn0 = x20; xn1 = x21;
        if (s < 15) barrier_lgkm();
    }
    __syncthreads();

#pragma unroll
    for (int r2 = 0; r2 < 2; ++r2)
#pragma unroll
        for (int t = 0; t < 3; ++t) {
            int gc = w * 48 + t * 16 + lm;
            int m = r2 * 16 + qd * 4;
#pragma unroll
            for (int rr = 0; rr < 4; ++rr) {
                ushort v = (ushort)f2bf1(acc[r2][t][rr]);
                if (gc < 128) sm.epi.c[(m + rr) * 136 + gc] = v;
                else          sm.epi.vt[(gc - 128) * 40 + (m + rr)] = v;
            }
        }
    __syncthreads();

    const int g16b = m0 >> 4;
    const int kt64 = m0 >> 6;
    const int tb   = (m0 >> 4) & 3;
    const int kcv  = (m0 >> 5) & 1;
#pragma unroll
    for (int ii = 0; ii < 3; ++ii) {
        int i = w + ii * 4;
        uint4 val;
        ushort* dst;
        if (i < 4) {
            int qt_l = i >> 1, kc = i & 1;
            val = *(const uint4*)(&sm.epi.c[(qt_l * 16 + lm) * 136 + kc * 32 + qd * 8]);
            dst = Qfm + (((size_t)(g16b + qt_l) * 2 + kc) * 64 + l) * 8;
        } else if (i < 8) {
            int j2 = i - 4, t_l = j2 >> 1, kc = j2 & 1;
            val = *(const uint4*)(&sm.epi.c[(t_l * 16 + lm) * 136 + 64 + kc * 32 + qd * 8]);
            dst = Kfm + (((size_t)((kt64 * 4 + tb + t_l) * 2 + kc)) * 64 + l) * 8;
        } else {
            int t = i - 8;
            val = *(const uint4*)(&sm.epi.vt[(t * 16 + lm) * 40 + qd * 8]);
            dst = Vfm + (((size_t)((kt64 * 4 + t) * 2 + kcv)) * 64 + l) * 8;
        }
        *(uint4*)dst = val;
    }
}

// ---------------- kernel 2: causal flash attention --------------------------
// XCD-pinned 1D grid (bt from blockIdx&7 -> each XCD touches ONE batch's
// K/V/Q), 8-way key split, pair-balanced, exp2 folded into Wq,
// dense frag-major bf16 O partials (2x dwordx4 per wave per half).
__global__ __launch_bounds__(256, 4) void flash(const ushort* __restrict__ Qfm,
                                                const ushort* __restrict__ Kfm,
                                                const ushort* __restrict__ Vfm,
                                                ushort* __restrict__ Opart,
                                                float* __restrict__ lpart) {
    __shared__ ushort plds[4][16 * 72];
    const int tid = threadIdx.x;
    const int wv = tid >> 6, l = tid & 63;
    const int lm = l & 15, qd = l >> 4;
    // decode: xcd = lin&7 (round-robin heuristic) -> bt pinned per XCD
    const int lin = blockIdx.x;
    const int xcd = lin & 7;
    const int bt = xcd >> 1;
    const int rest = lin >> 3;          // 0..127
    const int pr = rest & 31;           // pair 0..31
    const int h = ((rest >> 5) << 1) | (xcd & 1);   // 0..7
    ushort* myp = plds[wv];

#pragma unroll 1
    for (int half = 0; half < 2; ++half) {
        const int qt = half ? (63 - pr) : pr;
        const int g16 = bt * 256 + qt * 4 + wv;

        bf16x8 qf0, qf1;
        {
            const ushort* qp = Qfm + ((size_t)g16 * 2) * 512 + l * 8;
            qf0 = ldfrag(qp);
            qf1 = ldfrag(qp + 512);
        }
        f32x4 o[4];
#pragma unroll
        for (int t = 0; t < 4; ++t) o[t] = (f32x4){0.f, 0.f, 0.f, 0.f};
        float lacc = 0.f;

#pragma unroll 1
        for (int kt = h; kt <= qt; kt += NSPLIT) {
            const ushort* kb = Kfm + ((size_t)(bt * 64 + kt) * 8) * 512;
            const ushort* vb = Vfm + ((size_t)(bt * 64 + kt) * 8) * 512;
            f32x4 sf[4];
#pragma unroll
            for (int t = 0; t < 4; ++t) sf[t] = (f32x4){0.f, 0.f, 0.f, 0.f};
#pragma unroll
            for (int t = 0; t < 4; ++t) {
                bf16x8 k0 = ldfrag(kb + (t * 2 + 0) * 512 + l * 8);
                bf16x8 k1 = ldfrag(kb + (t * 2 + 1) * 512 + l * 8);
                sf[t] = __builtin_amdgcn_mfma_f32_16x16x32_bf16(k0, qf0, sf[t], 0, 0, 0);
                sf[t] = __builtin_amdgcn_mfma_f32_16x16x32_bf16(k1, qf1, sf[t], 0, 0, 0);
            }
            uint4 vu[4][2];
#pragma unroll
            for (int t = 0; t < 4; ++t) {
                vu[t][0] = *(const uint4*)(vb + (t * 2 + 0) * 512 + l * 8);
                vu[t][1] = *(const uint4*)(vb + (t * 2 + 1) * 512 + l * 8);
            }
            ushort* wp = myp + lm * 72 + qd * 4;
            if (kt != qt) {            // fully unmasked tile
#pragma unroll
                for (int t = 0; t < 4; ++t) {
                    float p0 = exp2f(sf[t][0]), p1 = exp2f(sf[t][1]);
                    float p2 = exp2f(sf[t][2]), p3 = exp2f(sf[t][3]);
                    lacc += (p0 + p1) + (p2 + p3);
                    *(uint2*)(wp + t * 16) = uint2{pk2(p0, p1), pk2(p2, p3)};
                }
            } else {                   // diagonal: t<wv full, t==wv tri, t>wv zero
#pragma unroll
                for (int t = 0; t < 4; ++t) {
                    if (t < wv) {
                        float p0 = exp2f(sf[t][0]), p1 = exp2f(sf[t][1]);
                        float p2 = exp2f(sf[t][2]), p3 = exp2f(sf[t][3]);
                        lacc += (p0 + p1) + (p2 + p3);
                        *(uint2*)(wp + t * 16) = uint2{pk2(p0, p1), pk2(p2, p3)};
                    } else if (t == wv) {
                        float p[4];
#pragma unroll
                        for (int rr = 0; rr < 4; ++rr) {
                            float pe = exp2f(sf[t][rr]);
                            if (qd * 4 + rr > lm) pe = 0.f;
                            lacc += pe;
                            p[rr] = pe;
                        }
                        *(uint2*)(wp + t * 16) = uint2{pk2(p[0], p[1]), pk2(p[2], p[3])};
                    } else {
                        *(uint2*)(wp + t * 16) = uint2{0u, 0u};
                    }
                }
            }
            __builtin_amdgcn_wave_barrier();
            __builtin_amdgcn_s_waitcnt(0xC07F);  // lgkmcnt(0): P committed (wave-private)
            __builtin_amdgcn_wave_barrier();
            bf16x8 pf0 = ldfrag(myp + lm * 72 + qd * 8);
            bf16x8 pf1 = ldfrag(myp + lm * 72 + 32 + qd * 8);
#pragma unroll
            for (int t = 0; t < 4; ++t) {
                o[t] = __builtin_amdgcn_mfma_f32_16x16x32_bf16(pf0, u2f(vu[t][0]), o[t], 0, 0, 0);
                o[t] = __builtin_amdgcn_mfma_f32_16x16x32_bf16(pf1, u2f(vu[t][1]), o[t], 0, 0, 0);
            }
            __builtin_amdgcn_wave_barrier();
        }
        lacc += __shfl_xor(lacc, 16);
        lacc += __shfl_xor(lacc, 32);

        // dense frag-major O partial: [h][g16][slot 2][lane][8] bf16
        ushort* ob = Opart + (((size_t)h * 1024 + g16) * 2) * 512 + l * 8;
        uint4 A = {pk2(o[0][0], o[0][1]), pk2(o[0][2], o[0][3]),
                   pk2(o[1][0], o[1][1]), pk2(o[1][2], o[1][3])};
        uint4 B = {pk2(o[2][0], o[2][1]), pk2(o[2][2], o[2][3]),
                   pk2(o[3][0], o[3][1]), pk2(o[3][2], o[3][3])};
        *(uint4*)ob = A;
        *(uint4*)(ob + 512) = B;
        if (qd == 0) lpart[(size_t)h * M_TOT + g16 * 16 + lm] = lacc;
    }
}

// ---------------- kernel 3: combine split-8 frag-major partials -------------
// one wave per g16 tile; dense dwordx4 reads, fp32 row-layout store to out.
__global__ __launch_bounds__(256) void combine(const ushort* __restrict__ Opart,
                                               const float* __restrict__ lpart,
                                               float* __restrict__ out) {
    const int tid = threadIdx.x;
    const int wv = tid >> 6, l = tid & 63;
    const int lm = l & 15, qd = l >> 4;
    const int g16 = blockIdx.x * 4 + wv;   // grid 256 -> 1024 tiles

    float s[4][4];
#pragma unroll
    for (int t = 0; t < 4; ++t)
#pragma unroll
        for (int rr = 0; rr < 4; ++rr) s[t][rr] = 0.f;
#pragma unroll
    for (int j = 0; j < NSPLIT; ++j) {
        const ushort* pb = Opart + (((size_t)j * 1024 + g16) * 2) * 512 + l * 8;
        uint4 a = *(const uint4*)pb;
        uint4 b = *(const uint4*)(pb + 512);
        s[0][0] += bf2f(a.x & 0xFFFFu); s[0][1] += bf2f(a.x >> 16);
        s[0][2] += bf2f(a.y & 0xFFFFu); s[0][3] += bf2f(a.y >> 16);
        s[1][0] += bf2f(a.z & 0xFFFFu); s[1][1] += bf2f(a.z >> 16);
        s[1][2] += bf2f(a.w & 0xFFFFu); s[1][3] += bf2f(a.w >> 16);
        s[2][0] += bf2f(b.x & 0xFFFFu); s[2][1] += bf2f(b.x >> 16);
        s[2][2] += bf2f(b.y & 0xFFFFu); s[2][3] += bf2f(b.y >> 16);
        s[3][0] += bf2f(b.z & 0xFFFFu); s[3][1] += bf2f(b.z >> 16);
        s[3][2] += bf2f(b.w & 0xFFFFu); s[3][3] += bf2f(b.w >> 16);
    }
    float inv[4];
#pragma unroll
    for (int rr = 0; rr < 4; ++rr) {
        float ls = 0.f;
#pragma unroll
        for (int j = 0; j < NSPLIT; ++j)
            ls += lpart[(size_t)j * M_TOT + g16 * 16 + qd * 4 + rr];
        inv[rr] = 1.0f / ls;
    }
#pragma unroll
    for (int rr = 0; rr < 4; ++rr) {
        size_t row = (size_t)g16 * 16 + qd * 4 + rr;
#pragma unroll
        for (int t = 0; t < 4; ++t)
            out[row * 64 + t * 16 + lm] = s[t][rr] * inv[rr];
    }
}

extern "C" void kernel_launch(void* const* d_in, const int* in_sizes, int n_in,
                              void* d_out, int out_size, void* d_ws, size_t ws_size,
                              hipStream_t stream) {
    const float* x  = (const float*)d_in[0];
    const float* Wq = (const float*)d_in[1];
    const float* Wk = (const float*)d_in[2];
    const float* Wv = (const float*)d_in[3];
    float* out = (float*)d_out;

    char* ws = (char*)d_ws;
    ushort* Wfm = (ushort*)(ws);                 // 384 KB
    ushort* Qfm = (ushort*)(ws + 393216);        // 2 MB
    ushort* Kfm = (ushort*)(ws + 2490368);       // 2 MB
    ushort* Vfm = (ushort*)(ws + 4587520);       // 2 MB
    ushort* Op  = (ushort*)(ws + 6684672);       // 16 MB frag-major bf16
    float*  lp  = (float*) (ws + 23461888);      // 512 KB

    wcvt<<<96, 256, 0, stream>>>(Wq, Wk, Wv, Wfm);
    qkv<<<512, 256, 0, stream>>>(x, Wfm, Qfm, Kfm, Vfm);
    flash<<<1024, 256, 0, stream>>>(Qfm, Kfm, Vfm, Op, lp);
    combine<<<256, 256, 0, stream>>>(Op, lp, out);
}